// Round 3
// baseline (4093.109 us; speedup 1.0000x reference)
//
#include <hip/hip_runtime.h>

// decoderLayer: B=8, L=1024, E=1024, H=16, dk=64.
// Inputs/outputs are FP32 (reference is jnp.float32; NaN forensics in rounds 1-2
// proved the float tensors are fp32: reading fp32 as bf16 pairs NaNs, and we saw NaN).
// Internal activations: bf16 scratch (48 MB ws), fp32 accumulation everywhere.
// d_out (8192x1024 fp32, 32 MB) doubles as the X1 scratch buffer.

typedef unsigned short u16;
typedef unsigned int u32;

#define Bv 8
#define Lv 1024
#define Ev 1024
#define Hv 16
#define DKv 64
#define Mv (Bv * Lv) // 8192 rows

__device__ __forceinline__ float bf_lo(u32 u) { return __uint_as_float(u << 16); }
__device__ __forceinline__ float bf_hi(u32 u) { return __uint_as_float(u & 0xffff0000u); }
// round-nearest-even two floats -> packed bf16 pair
__device__ __forceinline__ u32 pack2(float a, float b) {
    u32 ua = __float_as_uint(a); ua += 0x7fffu + ((ua >> 16) & 1u);
    u32 ub = __float_as_uint(b); ub += 0x7fffu + ((ub >> 16) & 1u);
    return (ua >> 16) | (ub & 0xffff0000u);
}

// ---- GEMM: C[8192,1024] = A[8192,1024] @ W[1024,1024] (+bias, relu).
//      A: fp32 (ABF=0) or bf16 scratch (ABF=1). W/bias: fp32. C: bf16 scratch.
//      fp32 accum. Rows with (r%L) >= lens[r/L] zeroed. Tile 128x128x16, 8x8/thread.
//      WATTN: W stored as (H=16, E=1024, dk=64); else flat (E, E). ----
template <int ABF, int WATTN, int BIAS, int RELU>
__global__ __launch_bounds__(256) void gemm_k(const void* __restrict__ A_,
                                              const float* __restrict__ W,
                                              const float* __restrict__ bias,
                                              u16* __restrict__ C,
                                              const int* __restrict__ lens) {
    __shared__ float As[16][128];
    __shared__ float Bs[16][128];
    const int tid = threadIdx.x;
    const int row0 = blockIdx.y * 128, col0 = blockIdx.x * 128;
    const int ty = tid >> 4, tx = tid & 15;
    const int lrow = tid & 127, khalf = tid >> 7; // A staging: 128 rows x 2 k-halves
    const int bk = tid >> 4;                      // B staging: 16 k x 16 col-groups
    const int bn = col0 + tx * 8;
    float acc[8][8] = {};

    for (int k0 = 0; k0 < Ev; k0 += 16) {
        // A tile: 8 consecutive k per thread
        {
            float av[8];
            const size_t aoff = (size_t)(row0 + lrow) * Ev + k0 + khalf * 8;
            if (ABF) {
                uint4 r = *(const uint4*)((const u16*)A_ + aoff);
                av[0] = bf_lo(r.x); av[1] = bf_hi(r.x); av[2] = bf_lo(r.y); av[3] = bf_hi(r.y);
                av[4] = bf_lo(r.z); av[5] = bf_hi(r.z); av[6] = bf_lo(r.w); av[7] = bf_hi(r.w);
            } else {
                const float* ap = (const float*)A_ + aoff;
                float4 r0 = *(const float4*)ap, r1 = *(const float4*)(ap + 4);
                av[0] = r0.x; av[1] = r0.y; av[2] = r0.z; av[3] = r0.w;
                av[4] = r1.x; av[5] = r1.y; av[6] = r1.z; av[7] = r1.w;
            }
#pragma unroll
            for (int j = 0; j < 8; j++) As[khalf * 8 + j][lrow] = av[j];
        }
        // B tile: 8 consecutive n per thread at row k0+bk (fp32 weights)
        {
            size_t widx;
            if (WATTN) widx = (size_t)(bn >> 6) * (Ev * DKv) + (size_t)(k0 + bk) * DKv + (bn & 63);
            else       widx = (size_t)(k0 + bk) * Ev + bn;
            float4 w0 = *(const float4*)(W + widx);
            float4 w1 = *(const float4*)(W + widx + 4);
            *(float4*)&Bs[bk][tx * 8] = w0;
            *(float4*)&Bs[bk][tx * 8 + 4] = w1;
        }
        __syncthreads();
#pragma unroll
        for (int k = 0; k < 16; k++) {
            float a[8], b[8];
            *(float4*)&a[0] = *(const float4*)&As[k][ty * 8];
            *(float4*)&a[4] = *(const float4*)&As[k][ty * 8 + 4];
            *(float4*)&b[0] = *(const float4*)&Bs[k][tx * 8];
            *(float4*)&b[4] = *(const float4*)&Bs[k][tx * 8 + 4];
#pragma unroll
            for (int i = 0; i < 8; i++)
#pragma unroll
                for (int j = 0; j < 8; j++) acc[i][j] += a[i] * b[j];
        }
        __syncthreads();
    }

    int len = lens[row0 / Lv];
    len = min(max(len, 0), Lv);
    float bvv[8] = {0.f, 0.f, 0.f, 0.f, 0.f, 0.f, 0.f, 0.f};
    if (BIAS) {
        float4 b0 = *(const float4*)(bias + bn);
        float4 b1 = *(const float4*)(bias + bn + 4);
        bvv[0] = b0.x; bvv[1] = b0.y; bvv[2] = b0.z; bvv[3] = b0.w;
        bvv[4] = b1.x; bvv[5] = b1.y; bvv[6] = b1.z; bvv[7] = b1.w;
    }
#pragma unroll
    for (int i = 0; i < 8; i++) {
        const int r = row0 + ty * 8 + i;
        const bool zero = ((r & (Lv - 1)) >= len);
        float v[8];
#pragma unroll
        for (int j = 0; j < 8; j++) {
            float x = acc[i][j] + bvv[j];
            if (RELU) x = fmaxf(x, 0.f);
            v[j] = zero ? 0.f : x;
        }
        uint4 w;
        w.x = pack2(v[0], v[1]); w.y = pack2(v[2], v[3]);
        w.z = pack2(v[4], v[5]); w.w = pack2(v[6], v[7]);
        *(uint4*)(C + (size_t)r * Ev + bn) = w;
    }
}

// ---- flash attention: 1 q-row/thread, 64-key LDS tiles, online softmax.
//      QZ/K/V bf16 scratch (B*L, E), head h at cols [h*64, h*64+64). Z written
//      IN PLACE over QZ (each block reads only its own Q region, before writing). ----
template <int CAUSAL>
__global__ __launch_bounds__(128) void attn_k(u16* __restrict__ QZ,
                                              const u16* __restrict__ K,
                                              const u16* __restrict__ V,
                                              const int* __restrict__ lens) {
    __shared__ float Kt[64][68];
    __shared__ float Vt[64][68];
    const int b = blockIdx.z, h = blockIdx.y, qt = blockIdx.x;
    const int t = threadIdx.x;
    const int iq = qt * 128 + t;
    int len = lens[b];
    len = min(max(len, 0), Lv);
    const bool active = iq < len;

    float q[64], o[64];
    const size_t qoff = ((size_t)(b * Lv + iq)) * Ev + h * DKv;
    {
        const uint4* qp = (const uint4*)(QZ + qoff);
#pragma unroll
        for (int i = 0; i < 8; i++) {
            uint4 r = qp[i];
            q[i * 8 + 0] = bf_lo(r.x); q[i * 8 + 1] = bf_hi(r.x);
            q[i * 8 + 2] = bf_lo(r.y); q[i * 8 + 3] = bf_hi(r.y);
            q[i * 8 + 4] = bf_lo(r.z); q[i * 8 + 5] = bf_hi(r.z);
            q[i * 8 + 6] = bf_lo(r.w); q[i * 8 + 7] = bf_hi(r.w);
        }
    }
#pragma unroll
    for (int d = 0; d < 64; d++) o[d] = 0.f;
    float m = -1e30f, l = 0.f;

    const int jEnd = CAUSAL ? min(len, qt * 128 + 128) : len;
    const int nt = (jEnd + 63) >> 6;
    const int jr = t >> 1, hf = (t & 1) * 32;

    for (int tile = 0; tile < nt; ++tile) {
        const int j0 = tile * 64;
        __syncthreads();
        {
            const size_t rbase = ((size_t)(b * Lv + j0 + jr)) * Ev + h * DKv + hf;
            const u16* kp = K + rbase;
            const u16* vp = V + rbase;
#pragma unroll
            for (int c = 0; c < 4; c++) {
                uint4 kw = *(const uint4*)(kp + c * 8);
                Kt[jr][hf + c * 8 + 0] = bf_lo(kw.x); Kt[jr][hf + c * 8 + 1] = bf_hi(kw.x);
                Kt[jr][hf + c * 8 + 2] = bf_lo(kw.y); Kt[jr][hf + c * 8 + 3] = bf_hi(kw.y);
                Kt[jr][hf + c * 8 + 4] = bf_lo(kw.z); Kt[jr][hf + c * 8 + 5] = bf_hi(kw.z);
                Kt[jr][hf + c * 8 + 6] = bf_lo(kw.w); Kt[jr][hf + c * 8 + 7] = bf_hi(kw.w);
                uint4 vw = *(const uint4*)(vp + c * 8);
                Vt[jr][hf + c * 8 + 0] = bf_lo(vw.x); Vt[jr][hf + c * 8 + 1] = bf_hi(vw.x);
                Vt[jr][hf + c * 8 + 2] = bf_lo(vw.y); Vt[jr][hf + c * 8 + 3] = bf_hi(vw.y);
                Vt[jr][hf + c * 8 + 4] = bf_lo(vw.z); Vt[jr][hf + c * 8 + 5] = bf_hi(vw.z);
                Vt[jr][hf + c * 8 + 6] = bf_lo(vw.w); Vt[jr][hf + c * 8 + 7] = bf_hi(vw.w);
            }
        }
        __syncthreads();
        if (active && (!CAUSAL || j0 <= iq)) {
            float p[64];
            float tmax = -1e30f;
#pragma unroll
            for (int j = 0; j < 64; j++) {
                float dot = 0.f;
#pragma unroll
                for (int d4 = 0; d4 < 16; d4++) {
                    float4 kv = *(const float4*)&Kt[j][d4 * 4];
                    dot += q[d4 * 4 + 0] * kv.x + q[d4 * 4 + 1] * kv.y +
                           q[d4 * 4 + 2] * kv.z + q[d4 * 4 + 3] * kv.w;
                }
                const int jj = j0 + j;
                const bool valid = CAUSAL ? (jj <= iq) : (jj < len);
                const float e = valid ? dot * 0.125f : -1e30f;
                p[j] = e;
                tmax = fmaxf(tmax, e);
            }
            const float mn = fmaxf(m, tmax);
            const float corr = __expf(m - mn);
            float lsum = 0.f;
#pragma unroll
            for (int j = 0; j < 64; j++) {
                const float pe = __expf(p[j] - mn);
                p[j] = pe;
                lsum += pe;
            }
#pragma unroll
            for (int d = 0; d < 64; d++) o[d] *= corr;
            l = l * corr + lsum;
            m = mn;
#pragma unroll
            for (int j = 0; j < 64; j++) {
                const float pj = p[j];
#pragma unroll
                for (int d4 = 0; d4 < 16; d4++) {
                    float4 vv = *(const float4*)&Vt[j][d4 * 4];
                    o[d4 * 4 + 0] += pj * vv.x;
                    o[d4 * 4 + 1] += pj * vv.y;
                    o[d4 * 4 + 2] += pj * vv.z;
                    o[d4 * 4 + 3] += pj * vv.w;
                }
            }
        }
    }
    const float inv = (active && l > 0.f) ? (1.f / l) : 0.f; // masked rows -> 0
    uint4* op = (uint4*)(QZ + qoff);
#pragma unroll
    for (int i = 0; i < 8; i++) {
        uint4 w;
        w.x = pack2(o[i * 8 + 0] * inv, o[i * 8 + 1] * inv);
        w.y = pack2(o[i * 8 + 2] * inv, o[i * 8 + 3] * inv);
        w.z = pack2(o[i * 8 + 4] * inv, o[i * 8 + 5] * inv);
        w.w = pack2(o[i * 8 + 6] * inv, o[i * 8 + 7] * inv);
        op[i] = w;
    }
}

// ---- residual + LayerNorm: out = LN(base + z)*g + b. z: bf16 scratch.
//      base: fp32 (BASEBF=0) or bf16 (BASEBF=1). out: fp32 (OUTF32=1) or bf16. ----
template <int BASEBF, int OUTF32>
__global__ __launch_bounds__(256) void ln_k(const void* __restrict__ base,
                                            const u16* __restrict__ z,
                                            const float* __restrict__ g,
                                            const float* __restrict__ bta,
                                            void* __restrict__ out) {
    __shared__ float r1[256], r2[256];
    const int row = blockIdx.x, t = threadIdx.x;
    const int c0 = t * 4;
    float v[4];
    if (BASEBF) {
        uint2 bu = *(const uint2*)((const u16*)base + (size_t)row * Ev + c0);
        v[0] = bf_lo(bu.x); v[1] = bf_hi(bu.x); v[2] = bf_lo(bu.y); v[3] = bf_hi(bu.y);
    } else {
        float4 f = *(const float4*)((const float*)base + (size_t)row * Ev + c0);
        v[0] = f.x; v[1] = f.y; v[2] = f.z; v[3] = f.w;
    }
    uint2 zu = *(const uint2*)(z + (size_t)row * Ev + c0);
    v[0] += bf_lo(zu.x); v[1] += bf_hi(zu.x); v[2] += bf_lo(zu.y); v[3] += bf_hi(zu.y);
    r1[t] = v[0] + v[1] + v[2] + v[3];
    r2[t] = v[0] * v[0] + v[1] * v[1] + v[2] * v[2] + v[3] * v[3];
    __syncthreads();
    for (int s = 128; s > 0; s >>= 1) {
        if (t < s) { r1[t] += r1[t + s]; r2[t] += r2[t + s]; }
        __syncthreads();
    }
    const float mu = r1[0] * (1.f / Ev);
    const float var = r2[0] * (1.f / Ev) - mu * mu;
    const float rinv = rsqrtf(fmaxf(var, 0.f) + 1e-5f);
    float4 gv = *(const float4*)(g + c0);
    float4 bv = *(const float4*)(bta + c0);
    float y[4];
    y[0] = (v[0] - mu) * rinv * gv.x + bv.x;
    y[1] = (v[1] - mu) * rinv * gv.y + bv.y;
    y[2] = (v[2] - mu) * rinv * gv.z + bv.z;
    y[3] = (v[3] - mu) * rinv * gv.w + bv.w;
    if (OUTF32) {
        float4 ow = {y[0], y[1], y[2], y[3]};
        *(float4*)((float*)out + (size_t)row * Ev + c0) = ow;
    } else {
        uint2 ow;
        ow.x = pack2(y[0], y[1]);
        ow.y = pack2(y[2], y[3]);
        *(uint2*)((u16*)out + (size_t)row * Ev + c0) = ow;
    }
}

extern "C" void kernel_launch(void* const* d_in, const int* in_sizes, int n_in,
                              void* d_out, int out_size, void* d_ws, size_t ws_size,
                              hipStream_t stream) {
    const float* x    = (const float*)d_in[0];
    const float* ctx  = (const float*)d_in[1];
    const int*   lens = (const int*)d_in[2];
    const float* Wq1 = (const float*)d_in[4];
    const float* Wk1 = (const float*)d_in[5];
    const float* Wv1 = (const float*)d_in[6];
    const float* Wq2 = (const float*)d_in[7];
    const float* Wk2 = (const float*)d_in[8];
    const float* Wv2 = (const float*)d_in[9];
    const float* g1 = (const float*)d_in[10], *b1 = (const float*)d_in[11];
    const float* g2 = (const float*)d_in[12], *b2 = (const float*)d_in[13];
    const float* g3 = (const float*)d_in[14], *b3 = (const float*)d_in[15];
    const float* fc1w = (const float*)d_in[16], *fc1b = (const float*)d_in[17];
    const float* fc2w = (const float*)d_in[18], *fc2b = (const float*)d_in[19];

    const size_t MM = (size_t)Mv * Ev;   // 8M elems; bf16 buffer = 16 MB
    u16* B1 = (u16*)d_ws;                // ws usage: 3 * 16 MB = 48 MB
    u16* B2 = B1 + MM;
    u16* B3 = B2 + MM;
    float* OUT = (float*)d_out;          // fp32; doubles as X1 scratch

    dim3 gG(8, 64), gA(8, Hv, Bv), gL(Mv);

    // self-attention (causal): Q,K,V from x (fp32 in, bf16 out)
    gemm_k<0, 1, 0, 0><<<gG, 256, 0, stream>>>(x, Wq1, nullptr, B1, lens);
    gemm_k<0, 1, 0, 0><<<gG, 256, 0, stream>>>(x, Wk1, nullptr, B2, lens);
    gemm_k<0, 1, 0, 0><<<gG, 256, 0, stream>>>(x, Wv1, nullptr, B3, lens);
    attn_k<1><<<gA, 128, 0, stream>>>(B1, B2, B3, lens);          // Z1 -> B1 (in place)
    ln_k<0, 1><<<gL, 256, 0, stream>>>(x, B1, g1, b1, OUT);       // X1 -> OUT (fp32)

    // cross-attention: Q,K from context (fp32); V from X1 (fp32 in OUT)
    gemm_k<0, 1, 0, 0><<<gG, 256, 0, stream>>>(ctx, Wq2, nullptr, B1, lens);
    gemm_k<0, 1, 0, 0><<<gG, 256, 0, stream>>>(ctx, Wk2, nullptr, B2, lens);
    gemm_k<0, 1, 0, 0><<<gG, 256, 0, stream>>>(OUT, Wv2, nullptr, B3, lens);
    attn_k<0><<<gA, 128, 0, stream>>>(B1, B2, B3, lens);          // Z2 -> B1 (in place)
    ln_k<0, 0><<<gL, 256, 0, stream>>>(OUT, B1, g2, b2, B2);      // X2 -> B2 (bf16)

    // FFN
    gemm_k<1, 0, 1, 1><<<gG, 256, 0, stream>>>(B2, fc1w, fc1b, B3, lens); // H -> B3
    gemm_k<1, 0, 1, 0><<<gG, 256, 0, stream>>>(B3, fc2w, fc2b, B1, lens); // Z3 -> B1
    ln_k<1, 1><<<gL, 256, 0, stream>>>(B2, B1, g3, b3, OUT);      // final -> OUT (fp32)
}

// Round 4
// 566.655 us; speedup vs baseline: 7.2233x; 7.2233x over previous
//
#include <hip/hip_runtime.h>

// decoderLayer B=8, L=1024, E=1024, H=16, dk=64. fp32 I/O, bf16 internals,
// fp32 accum via bf16 MFMA (16x16x32). ws: 8 transposed bf16 weights (16MB) +
// 4 bf16 activation buffers (64MB) = 80MB. d_out doubles as xb/cb bf16 scratch.

typedef unsigned short u16;
typedef unsigned int u32;
typedef __attribute__((ext_vector_type(8))) short bf16x8;
typedef __attribute__((ext_vector_type(4))) float f32x4;

#define Bv 8
#define Lv 1024
#define Ev 1024
#define Hv 16
#define DKv 64
#define Mv (Bv * Lv)

__device__ __forceinline__ u16 f2bf(float f) {
    u32 u = __float_as_uint(f);
    u += 0x7fffu + ((u >> 16) & 1u);
    return (u16)(u >> 16);
}
__device__ __forceinline__ u32 pack2(float a, float b) {
    u32 ua = __float_as_uint(a); ua += 0x7fffu + ((ua >> 16) & 1u);
    u32 ub = __float_as_uint(b); ub += 0x7fffu + ((ub >> 16) & 1u);
    return (ua >> 16) | (ub & 0xffff0000u);
}

// fp32 -> bf16 convert (8M elems)
__global__ __launch_bounds__(256) void conv_k(const float* __restrict__ s, u16* __restrict__ d) {
    int i4 = (blockIdx.x * 256 + threadIdx.x) * 4;
    float4 v = *(const float4*)(s + i4);
    uint2 o = {pack2(v.x, v.y), pack2(v.z, v.w)};
    *(uint2*)(d + i4) = o;
}

// attn weight (H,E,dk) fp32 -> Wt[n=h*64+d][k=e] bf16
__global__ __launch_bounds__(256) void trans_attn(const float* __restrict__ s, u16* __restrict__ d) {
    __shared__ float t[32][33];
    const int d0 = blockIdx.x * 32, e0 = blockIdx.y * 32, h = blockIdx.z;
    const int tx = threadIdx.x, ty = threadIdx.y;
#pragma unroll
    for (int i = 0; i < 4; i++)
        t[ty + i * 8][tx] = s[(size_t)h * Ev * DKv + (size_t)(e0 + ty + i * 8) * DKv + d0 + tx];
    __syncthreads();
#pragma unroll
    for (int i = 0; i < 4; i++)
        d[(size_t)(h * DKv + d0 + ty + i * 8) * Ev + e0 + tx] = f2bf(t[tx][ty + i * 8]);
}

// fc weight (E,E) [k][n] fp32 -> Wt[n][k] bf16
__global__ __launch_bounds__(256) void trans_fc(const float* __restrict__ s, u16* __restrict__ d) {
    __shared__ float t[32][33];
    const int n0 = blockIdx.x * 32, k0 = blockIdx.y * 32;
    const int tx = threadIdx.x, ty = threadIdx.y;
#pragma unroll
    for (int i = 0; i < 4; i++)
        t[ty + i * 8][tx] = s[(size_t)(k0 + ty + i * 8) * Ev + n0 + tx];
    __syncthreads();
#pragma unroll
    for (int i = 0; i < 4; i++)
        d[(size_t)(n0 + ty + i * 8) * Ev + k0 + tx] = f2bf(t[tx][ty + i * 8]);
}

// ---- MFMA GEMM: C[8192,1024] = A[8192,1024](bf16) @ Wt[n][k](bf16)^T.
//      Tile 128x128, BK=64, 4 waves (2x2 of 64x64). Fragment-ordered LDS.
//      TRANSOUT: write C^T layout [n][8192] (for V). Rows (r%1024)>=len zeroed. ----
template <int BIAS, int RELU, int TRANSOUT>
__global__ __launch_bounds__(256) void mgemm(const u16* __restrict__ A,
                                             const u16* __restrict__ Wt,
                                             const float* __restrict__ bias,
                                             u16* __restrict__ C,
                                             const int* __restrict__ lens) {
    __shared__ u16 Alds[16 * 520]; // 16 frag-blocks x (64 lanes*8 + 8 pad) u16
    __shared__ u16 Blds[16 * 520];
    const int tid = threadIdx.x;
    const int w = tid >> 6, l = tid & 63;
    const int lc = l & 15, lq = l >> 4;
    const int row0 = blockIdx.y * 128, col0 = blockIdx.x * 128;
    const int wm4 = (w >> 1) * 4, wn4 = (w & 1) * 4; // wave tile in 16-units

    f32x4 acc[4][4];
#pragma unroll
    for (int i = 0; i < 4; i++)
#pragma unroll
        for (int j = 0; j < 4; j++) acc[i][j] = (f32x4){0.f, 0.f, 0.f, 0.f};

    for (int k0 = 0; k0 < Ev; k0 += 64) {
        const u16* Ag = A + (size_t)row0 * Ev + k0;
        const u16* Bg = Wt + (size_t)col0 * Ev + k0;
#pragma unroll
        for (int i = 0; i < 4; i++) {
            int s = i * 256 + tid;
            int row = s >> 3, g = s & 7;
            uint4 va = *(const uint4*)(Ag + (size_t)row * Ev + g * 8);
            uint4 vb = *(const uint4*)(Bg + (size_t)row * Ev + g * 8);
            int off = ((row >> 4) * 2 + (g >> 2)) * 520 + ((g & 3) * 16 + (row & 15)) * 8;
            *(uint4*)(Alds + off) = va;
            *(uint4*)(Blds + off) = vb;
        }
        __syncthreads();
#pragma unroll
        for (int km = 0; km < 2; km++) {
            bf16x8 af[4], bfr[4];
#pragma unroll
            for (int mt = 0; mt < 4; mt++)
                af[mt] = *(const bf16x8*)(Alds + ((wm4 + mt) * 2 + km) * 520 + l * 8);
#pragma unroll
            for (int nt = 0; nt < 4; nt++)
                bfr[nt] = *(const bf16x8*)(Blds + ((wn4 + nt) * 2 + km) * 520 + l * 8);
#pragma unroll
            for (int mt = 0; mt < 4; mt++)
#pragma unroll
                for (int nt = 0; nt < 4; nt++)
                    acc[mt][nt] = __builtin_amdgcn_mfma_f32_16x16x32_bf16(
                        af[mt], bfr[nt], acc[mt][nt], 0, 0, 0);
        }
        __syncthreads();
    }

    int len = lens[row0 >> 10];
    len = min(max(len, 0), Lv);
    float bv[4];
#pragma unroll
    for (int nt = 0; nt < 4; nt++)
        bv[nt] = BIAS ? bias[col0 + wn4 * 16 + nt * 16 + lc] : 0.f;

#pragma unroll
    for (int mt = 0; mt < 4; mt++) {
        const int rowb = row0 + wm4 * 16 + mt * 16 + lq * 4;
#pragma unroll
        for (int nt = 0; nt < 4; nt++) {
            const int col = col0 + wn4 * 16 + nt * 16 + lc;
            float v[4];
#pragma unroll
            for (int r = 0; r < 4; r++) {
                float x = acc[mt][nt][r] + bv[nt];
                if (RELU) x = fmaxf(x, 0.f);
                v[r] = (((rowb + r) & (Lv - 1)) >= len) ? 0.f : x;
            }
            if (TRANSOUT) {
                uint2 o = {pack2(v[0], v[1]), pack2(v[2], v[3])};
                *(uint2*)(C + (size_t)col * Mv + rowb) = o;
            } else {
#pragma unroll
                for (int r = 0; r < 4; r++)
                    C[(size_t)(rowb + r) * Ev + col] = f2bf(v[r]);
            }
        }
    }
}

// ---- MFMA flash attention. Q/Z: [row][E] bf16 head-offset (in-place).
//      K: [row][E] bf16. VT: [n=h*64+d][8192] bf16. 64 q-rows/block, 4 waves
//      (16 q each), 128-key tiles, online softmax, P via LDS round-trip. ----
template <int CAUSAL>
__global__ __launch_bounds__(256) void mattn(u16* __restrict__ QZ,
                                             const u16* __restrict__ K,
                                             const u16* __restrict__ VT,
                                             const int* __restrict__ lens) {
    __shared__ u16 Kt[128 * 72];      // [key][kd], stride 72 (pad)
    __shared__ u16 Vt[64 * 136];      // [d][key], stride 136 (pad)
    __shared__ u16 Pw[4 * 16 * 136];  // per-wave P[q][key], stride 136
    const int b = blockIdx.z, h = blockIdx.y, qb = blockIdx.x;
    const int q0 = qb * 64;
    const int tid = threadIdx.x;
    const int w = tid >> 6, l = tid & 63;
    const int lc = l & 15, lq = l >> 4;
    int len = lens[b];
    len = min(max(len, 0), Lv);

    if (q0 >= len) { // fully masked q-block: zero its Z region
        const int row = q0 + (tid >> 2), cc = (tid & 3) * 16;
        uint4 z4 = {0u, 0u, 0u, 0u};
        uint4* p = (uint4*)(QZ + (size_t)(b * Lv + row) * Ev + h * DKv + cc);
        p[0] = z4; p[1] = z4;
        return;
    }

    // Q fragments (A-layout): lane: Q[q0+w*16+lc][km*32 + lq*8 + j]
    const size_t qrow = (size_t)(b * Lv + q0 + w * 16 + lc) * Ev + h * DKv;
    bf16x8 qf[2];
    qf[0] = *(const bf16x8*)(QZ + qrow + lq * 8);
    qf[1] = *(const bf16x8*)(QZ + qrow + 32 + lq * 8);

    f32x4 of[4];
#pragma unroll
    for (int i = 0; i < 4; i++) of[i] = (f32x4){0.f, 0.f, 0.f, 0.f};
    float mrow[4] = {-1e30f, -1e30f, -1e30f, -1e30f};
    float lrow[4] = {0.f, 0.f, 0.f, 0.f};

    const int jend = CAUSAL ? min(len, q0 + 64) : len;
    const int ntiles = (jend + 127) >> 7;

    for (int kt = 0; kt < ntiles; kt++) {
        const int key0 = kt * 128;
        __syncthreads();
        { // stage K tile: 128 keys x 64 kd
            const u16* kg = K + (size_t)(b * Lv + key0 + (tid & 127)) * Ev + h * DKv + (tid >> 7) * 32;
            u16* kd = Kt + (tid & 127) * 72 + (tid >> 7) * 32;
#pragma unroll
            for (int c = 0; c < 4; c++) *(uint4*)(kd + c * 8) = *(const uint4*)(kg + c * 8);
            // stage V^T tile: 64 d x 128 keys
            const u16* vg = VT + (size_t)(h * DKv + (tid >> 2)) * Mv + b * Lv + key0 + (tid & 3) * 32;
            u16* vd = Vt + (tid >> 2) * 136 + (tid & 3) * 32;
#pragma unroll
            for (int c = 0; c < 4; c++) *(uint4*)(vd + c * 8) = *(const uint4*)(vg + c * 8);
        }
        __syncthreads();

        // S = Q K^T (8 n-tiles of 16 keys, K-dim 64 = 2 MFMAs)
        f32x4 sf[8];
#pragma unroll
        for (int nt = 0; nt < 8; nt++) {
            bf16x8 b0 = *(const bf16x8*)(Kt + (nt * 16 + lc) * 72 + lq * 8);
            bf16x8 b1 = *(const bf16x8*)(Kt + (nt * 16 + lc) * 72 + 32 + lq * 8);
            f32x4 s = (f32x4){0.f, 0.f, 0.f, 0.f};
            s = __builtin_amdgcn_mfma_f32_16x16x32_bf16(qf[0], b0, s, 0, 0, 0);
            s = __builtin_amdgcn_mfma_f32_16x16x32_bf16(qf[1], b1, s, 0, 0, 0);
            sf[nt] = s;
        }
        // mask + scale; row max
        float tmax[4] = {-1e30f, -1e30f, -1e30f, -1e30f};
#pragma unroll
        for (int nt = 0; nt < 8; nt++) {
            const int jj = key0 + nt * 16 + lc;
            const bool jv = jj < len;
#pragma unroll
            for (int r = 0; r < 4; r++) {
                const int iq = q0 + w * 16 + lq * 4 + r;
                const bool valid = jv && (!CAUSAL || jj <= iq);
                float e = valid ? sf[nt][r] * 0.125f : -1e30f;
                sf[nt][r] = e;
                tmax[r] = fmaxf(tmax[r], e);
            }
        }
#pragma unroll
        for (int r = 0; r < 4; r++) {
#pragma unroll
            for (int d = 1; d < 16; d <<= 1)
                tmax[r] = fmaxf(tmax[r], __shfl_xor(tmax[r], d, 64));
        }
        float alpha[4], mnew[4], psum[4];
#pragma unroll
        for (int r = 0; r < 4; r++) {
            mnew[r] = fmaxf(mrow[r], tmax[r]);
            alpha[r] = __expf(mrow[r] - mnew[r]);
            psum[r] = 0.f;
        }
#pragma unroll
        for (int nt = 0; nt < 8; nt++)
#pragma unroll
            for (int r = 0; r < 4; r++) {
                float p = __expf(sf[nt][r] - mnew[r]);
                sf[nt][r] = p;
                psum[r] += p;
            }
#pragma unroll
        for (int r = 0; r < 4; r++) {
#pragma unroll
            for (int d = 1; d < 16; d <<= 1) psum[r] += __shfl_xor(psum[r], d, 64);
            lrow[r] = lrow[r] * alpha[r] + psum[r];
            mrow[r] = mnew[r];
        }
#pragma unroll
        for (int nd = 0; nd < 4; nd++)
#pragma unroll
            for (int r = 0; r < 4; r++) of[nd][r] *= alpha[r];
        // write P (C-layout -> LDS, bf16)
        u16* pw = Pw + w * (16 * 136);
#pragma unroll
        for (int nt = 0; nt < 8; nt++)
#pragma unroll
            for (int r = 0; r < 4; r++)
                pw[(lq * 4 + r) * 136 + nt * 16 + lc] = f2bf(sf[nt][r]);
        // O += P V  (A-layout P from LDS; B from V^T tile)
#pragma unroll
        for (int nd = 0; nd < 4; nd++) {
#pragma unroll
            for (int km = 0; km < 4; km++) {
                bf16x8 pa = *(const bf16x8*)(pw + lc * 136 + km * 32 + lq * 8);
                bf16x8 vb = *(const bf16x8*)(Vt + (nd * 16 + lc) * 136 + km * 32 + lq * 8);
                of[nd] = __builtin_amdgcn_mfma_f32_16x16x32_bf16(pa, vb, of[nd], 0, 0, 0);
            }
        }
    }

    float inv[4];
#pragma unroll
    for (int r = 0; r < 4; r++) {
        const int iq = q0 + w * 16 + lq * 4 + r;
        inv[r] = (iq < len && lrow[r] > 0.f) ? (1.f / lrow[r]) : 0.f;
    }
#pragma unroll
    for (int nd = 0; nd < 4; nd++)
#pragma unroll
        for (int r = 0; r < 4; r++)
            QZ[(size_t)(b * Lv + q0 + w * 16 + lq * 4 + r) * Ev + h * DKv + nd * 16 + lc] =
                f2bf(of[nd][r] * inv[r]);
}

__device__ __forceinline__ float bf_lo(u32 u) { return __uint_as_float(u << 16); }
__device__ __forceinline__ float bf_hi(u32 u) { return __uint_as_float(u & 0xffff0000u); }

// ---- residual + LayerNorm: out = LN(base + z)*g + b. z bf16.
//      base fp32 (BASEBF=0) or bf16; out fp32 (OUTF32=1) or bf16. ----
template <int BASEBF, int OUTF32>
__global__ __launch_bounds__(256) void ln_k(const void* __restrict__ base,
                                            const u16* __restrict__ z,
                                            const float* __restrict__ g,
                                            const float* __restrict__ bta,
                                            void* __restrict__ out) {
    __shared__ float r1[256], r2[256];
    const int row = blockIdx.x, t = threadIdx.x;
    const int c0 = t * 4;
    float v[4];
    if (BASEBF) {
        uint2 bu = *(const uint2*)((const u16*)base + (size_t)row * Ev + c0);
        v[0] = bf_lo(bu.x); v[1] = bf_hi(bu.x); v[2] = bf_lo(bu.y); v[3] = bf_hi(bu.y);
    } else {
        float4 f = *(const float4*)((const float*)base + (size_t)row * Ev + c0);
        v[0] = f.x; v[1] = f.y; v[2] = f.z; v[3] = f.w;
    }
    uint2 zu = *(const uint2*)(z + (size_t)row * Ev + c0);
    v[0] += bf_lo(zu.x); v[1] += bf_hi(zu.x); v[2] += bf_lo(zu.y); v[3] += bf_hi(zu.y);
    r1[t] = v[0] + v[1] + v[2] + v[3];
    r2[t] = v[0] * v[0] + v[1] * v[1] + v[2] * v[2] + v[3] * v[3];
    __syncthreads();
    for (int s = 128; s > 0; s >>= 1) {
        if (t < s) { r1[t] += r1[t + s]; r2[t] += r2[t + s]; }
        __syncthreads();
    }
    const float mu = r1[0] * (1.f / Ev);
    const float var = r2[0] * (1.f / Ev) - mu * mu;
    const float rinv = rsqrtf(fmaxf(var, 0.f) + 1e-5f);
    float4 gv = *(const float4*)(g + c0);
    float4 bv = *(const float4*)(bta + c0);
    float y[4];
    y[0] = (v[0] - mu) * rinv * gv.x + bv.x;
    y[1] = (v[1] - mu) * rinv * gv.y + bv.y;
    y[2] = (v[2] - mu) * rinv * gv.z + bv.z;
    y[3] = (v[3] - mu) * rinv * gv.w + bv.w;
    if (OUTF32) {
        float4 ow = {y[0], y[1], y[2], y[3]};
        *(float4*)((float*)out + (size_t)row * Ev + c0) = ow;
    } else {
        uint2 ow = {pack2(y[0], y[1]), pack2(y[2], y[3])};
        *(uint2*)((u16*)out + (size_t)row * Ev + c0) = ow;
    }
}

extern "C" void kernel_launch(void* const* d_in, const int* in_sizes, int n_in,
                              void* d_out, int out_size, void* d_ws, size_t ws_size,
                              hipStream_t stream) {
    const float* x    = (const float*)d_in[0];
    const float* ctx  = (const float*)d_in[1];
    const int*   lens = (const int*)d_in[2];
    const float* Wq1 = (const float*)d_in[4];
    const float* Wk1 = (const float*)d_in[5];
    const float* Wv1 = (const float*)d_in[6];
    const float* Wq2 = (const float*)d_in[7];
    const float* Wk2 = (const float*)d_in[8];
    const float* Wv2 = (const float*)d_in[9];
    const float* g1 = (const float*)d_in[10], *b1 = (const float*)d_in[11];
    const float* g2 = (const float*)d_in[12], *b2 = (const float*)d_in[13];
    const float* g3 = (const float*)d_in[14], *b3 = (const float*)d_in[15];
    const float* fc1w = (const float*)d_in[16], *fc1b = (const float*)d_in[17];
    const float* fc2w = (const float*)d_in[18], *fc2b = (const float*)d_in[19];

    const size_t WSZ = (size_t)Ev * Ev;  // 1M elems
    const size_t MM  = (size_t)Mv * Ev;  // 8M elems (bf16 buffer = 16 MB)
    u16* WT = (u16*)d_ws;                // 8 transposed bf16 weights: 16 MB
    u16* Wtq1 = WT + 0 * WSZ, *Wtk1 = WT + 1 * WSZ, *Wtv1 = WT + 2 * WSZ;
    u16* Wtq2 = WT + 3 * WSZ, *Wtk2 = WT + 4 * WSZ, *Wtv2 = WT + 5 * WSZ;
    u16* Wtf1 = WT + 6 * WSZ, *Wtf2 = WT + 7 * WSZ;
    u16* B1 = WT + 8 * WSZ;              // 4 x 16 MB activation buffers
    u16* B2 = B1 + MM;
    u16* B3 = B2 + MM;
    u16* B4 = B3 + MM;
    u16* xb = (u16*)d_out;               // bf16 copies of x/ctx live in d_out
    u16* cb = xb + MM;                   //  (final LN overwrites d_out last)

    dim3 gC(Mv * Ev / 1024), gTA(2, 32, Hv), gTF(32, 32), bT(32, 8);
    dim3 gG(8, 64), gA(16, Hv, Bv), gL(Mv);

    conv_k<<<gC, 256, 0, stream>>>(x, xb);
    conv_k<<<gC, 256, 0, stream>>>(ctx, cb);
    trans_attn<<<gTA, bT, 0, stream>>>(Wq1, Wtq1);
    trans_attn<<<gTA, bT, 0, stream>>>(Wk1, Wtk1);
    trans_attn<<<gTA, bT, 0, stream>>>(Wv1, Wtv1);
    trans_attn<<<gTA, bT, 0, stream>>>(Wq2, Wtq2);
    trans_attn<<<gTA, bT, 0, stream>>>(Wk2, Wtk2);
    trans_attn<<<gTA, bT, 0, stream>>>(Wv2, Wtv2);
    trans_fc<<<gTF, bT, 0, stream>>>(fc1w, Wtf1);
    trans_fc<<<gTF, bT, 0, stream>>>(fc2w, Wtf2);

    // self-attention (causal)
    mgemm<0, 0, 0><<<gG, 256, 0, stream>>>(xb, Wtq1, nullptr, B1, lens); // Q1
    mgemm<0, 0, 0><<<gG, 256, 0, stream>>>(xb, Wtk1, nullptr, B2, lens); // K1
    mgemm<0, 0, 1><<<gG, 256, 0, stream>>>(xb, Wtv1, nullptr, B3, lens); // V1^T
    mattn<1><<<gA, 256, 0, stream>>>(B1, B2, B3, lens);                  // Z1 -> B1
    ln_k<0, 0><<<gL, 256, 0, stream>>>(x, B1, g1, b1, B2);               // X1 -> B2 (bf16)

    // cross-attention: Q,K from ctx; V from X1
    mgemm<0, 0, 0><<<gG, 256, 0, stream>>>(cb, Wtq2, nullptr, B1, lens); // Q2
    mgemm<0, 0, 0><<<gG, 256, 0, stream>>>(cb, Wtk2, nullptr, B3, lens); // K2
    mgemm<0, 0, 1><<<gG, 256, 0, stream>>>(B2, Wtv2, nullptr, B4, lens); // V2^T
    mattn<0><<<gA, 256, 0, stream>>>(B1, B3, B4, lens);                  // Z2 -> B1
    ln_k<1, 0><<<gL, 256, 0, stream>>>(B2, B1, g2, b2, B3);              // X2 -> B3 (bf16)

    // FFN
    mgemm<1, 1, 0><<<gG, 256, 0, stream>>>(B3, Wtf1, fc1b, B1, lens);    // H -> B1
    mgemm<1, 0, 0><<<gG, 256, 0, stream>>>(B1, Wtf2, fc2b, B4, lens);    // Z3 -> B4
    ln_k<1, 1><<<gL, 256, 0, stream>>>(B3, B4, g3, b3, d_out);           // final (fp32)
}